// Round 1
// baseline (206.863 us; speedup 1.0000x reference)
//
#include <hip/hip_runtime.h>
#include <hip/hip_bf16.h>

typedef __bf16 bf16;
typedef bf16 bf16x8 __attribute__((ext_vector_type(8)));
typedef bf16 bf16x4 __attribute__((ext_vector_type(4)));
typedef float f32x4 __attribute__((ext_vector_type(4)));
typedef unsigned int u32;

#define S_LEN 2048
#define DM 1024
#define NH 16
#define DK 64
#define MTOK 4096  // B*S

// async global->LDS, 16B per lane; LDS dest is wave-uniform base + lane*16
__device__ __forceinline__ void gld16(const void* g, void* l) {
  __builtin_amdgcn_global_load_lds(
      (const __attribute__((address_space(1))) u32*)g,
      (__attribute__((address_space(3))) u32*)l, 16, 0, 0);
}

// ---------------------------------------------------------------- convert
__global__ void cvt_f32_bf16_k(const float* __restrict__ src, bf16* __restrict__ dst, int n4) {
  int i = blockIdx.x * blockDim.x + threadIdx.x;
  if (i >= n4) return;
  f32x4 v = reinterpret_cast<const f32x4*>(src)[i];
  bf16x4 o;
  o[0] = (bf16)v[0]; o[1] = (bf16)v[1]; o[2] = (bf16)v[2]; o[3] = (bf16)v[3];
  reinterpret_cast<bf16x4*>(dst)[i] = o;
}

// ---------------------------------------------------------------- QKV GEMM
// C[m][n] = sum_k A[m][k] * W[n][k]  (+bias), 128x128 tile, BK=64, 4 waves 2x2.
// LDS XOR-swizzle (byte ^= (row&7)<<4) realized via pre-swizzled GLOBAL source
// (global_load_lds writes linearly), swizzled ds_read on the consume side.
__global__ __launch_bounds__(256) void gemm_qkv(
    const bf16* __restrict__ A,
    const bf16* __restrict__ Wq, const bf16* __restrict__ Wk, const bf16* __restrict__ Wv,
    const float* __restrict__ Bq, const float* __restrict__ Bk, const float* __restrict__ Bv,
    bf16* __restrict__ Qo, bf16* __restrict__ Ko, bf16* __restrict__ Vt) {
  __shared__ char smem[32768];
  char* As = smem;
  char* Bs = smem + 16384;
  const int z = blockIdx.z;
  const bf16* W = (z == 0) ? Wq : (z == 1) ? Wk : Wv;
  const float* bias = (z == 0) ? Bq : (z == 1) ? Bk : Bv;
  const int m0 = blockIdx.y * 128;
  const int n0 = blockIdx.x * 128;
  const int tid = threadIdx.x;
  const int lane = tid & 63;
  const int wid = tid >> 6;
  const int wr = (wid >> 1) * 64, wc = (wid & 1) * 64;
  const int scb = 16 * ((lane & 7) ^ (lane >> 3));  // pre-swizzled source col bytes
  const int lr8 = lane >> 3;

  f32x4 acc[4][4] = {};

  for (int k0 = 0; k0 < DM; k0 += 64) {
#pragma unroll
    for (int c = 0; c < 4; ++c) {
      const int chunk = wid * 4 + c;       // 16 chunks of 1KB (8 rows each)
      const int row = chunk * 8 + lr8;
      gld16((const char*)A + ((size_t)(m0 + row) * DM + k0) * 2 + scb, As + chunk * 1024);
      gld16((const char*)W + ((size_t)(n0 + row) * DM + k0) * 2 + scb, Bs + chunk * 1024);
    }
    __syncthreads();
#pragma unroll
    for (int kk = 0; kk < 2; ++kk) {
      bf16x8 af[4], bfr[4];
#pragma unroll
      for (int i = 0; i < 4; ++i) {
        const int ar = wr + i * 16 + (lane & 15);
        af[i] = *reinterpret_cast<const bf16x8*>(
            As + ar * 128 + ((kk * 64 + 16 * (lane >> 4)) ^ ((ar & 7) << 4)));
        const int br = wc + i * 16 + (lane & 15);
        bfr[i] = *reinterpret_cast<const bf16x8*>(
            Bs + br * 128 + ((kk * 64 + 16 * (lane >> 4)) ^ ((br & 7) << 4)));
      }
#pragma unroll
      for (int i = 0; i < 4; ++i)
#pragma unroll
        for (int j = 0; j < 4; ++j)
          acc[i][j] = __builtin_amdgcn_mfma_f32_16x16x32_bf16(af[i], bfr[j], acc[i][j], 0, 0, 0);
    }
    __syncthreads();
  }

  // epilogue: D row=(lane>>4)*4+r, col=lane&15 (verified m89 layout)
  const int bIdx = m0 >> 11;  // token tile -> batch (2048 rows per batch)
  const int r4 = (lane >> 4) * 4;
#pragma unroll
  for (int i = 0; i < 4; ++i) {
    const int mrow = m0 + wr + i * 16 + r4;
    const int srow = mrow & (S_LEN - 1);
#pragma unroll
    for (int j = 0; j < 4; ++j) {
      const int n = n0 + wc + j * 16 + (lane & 15);
      const int h = n >> 6, d = n & 63;
      const int bh = bIdx * NH + h;
      const float bs = bias[n];
      if (z == 0) {  // Q: scale by 1/sqrt(dk), layout [bh][s][d]
#pragma unroll
        for (int r = 0; r < 4; ++r)
          Qo[((size_t)bh * S_LEN + srow + r) * DK + d] = (bf16)((acc[i][j][r] + bs) * 0.125f);
      } else if (z == 1) {  // K: [bh][s][d]
#pragma unroll
        for (int r = 0; r < 4; ++r)
          Ko[((size_t)bh * S_LEN + srow + r) * DK + d] = (bf16)(acc[i][j][r] + bs);
      } else {  // V transposed: [bh][d][s], 4 consecutive s -> one 8B store
        bf16x4 pk;
#pragma unroll
        for (int r = 0; r < 4; ++r) pk[r] = (bf16)(acc[i][j][r] + bs);
        *reinterpret_cast<bf16x4*>(&Vt[((size_t)bh * DK + d) * S_LEN + srow]) = pk;
      }
    }
  }
}

// ---------------------------------------------------------------- attention
// 1 block = 64 Q rows of one (b,h); 4 waves x 16 rows. KV tile = 64. Causal.
__global__ __launch_bounds__(256) void attn_fwd(
    const bf16* __restrict__ Q, const bf16* __restrict__ K,
    const bf16* __restrict__ Vt, bf16* __restrict__ O) {
  __shared__ char smem[24576];
  char* Ks = smem;          // [64 kv][128B d], swizzled
  char* Vs = smem + 8192;   // [64 d][128B kv], swizzled
  char* Ps = smem + 16384;  // per-wave [16 q][128B k], swizzled
  const int qt = gridDim.x - 1 - blockIdx.x;  // heavy tiles first
  const int bh = blockIdx.y;
  const int tid = threadIdx.x, lane = tid & 63, wid = tid >> 6;
  const int q0 = qt * 64;
  const int scb = 16 * ((lane & 7) ^ (lane >> 3));
  const int l15 = lane & 15;
  const int lg = lane >> 4;
  const int r4 = lg * 4;

  // Q fragments held in registers for the whole block row
  const bf16* qptr = Q + ((size_t)bh * S_LEN + q0 + wid * 16 + l15) * DK + 8 * lg;
  const bf16x8 qf0 = *reinterpret_cast<const bf16x8*>(qptr);
  const bf16x8 qf1 = *reinterpret_cast<const bf16x8*>(qptr + 32);

  f32x4 o[4] = {};
  float m_r[4], l_r[4];
#pragma unroll
  for (int r = 0; r < 4; ++r) { m_r[r] = -3.0e38f; l_r[r] = 0.f; }

  const int nt = qt + 1;
  for (int t = 0; t < nt; ++t) {
    const int kv0 = t * 64;
#pragma unroll
    for (int c = 0; c < 2; ++c) {
      const int chunk = wid * 2 + c;  // 8 chunks of 1KB
      const int row = chunk * 8 + (lane >> 3);
      gld16((const char*)K + ((size_t)(bh * S_LEN + kv0 + row)) * 128 + scb, Ks + chunk * 1024);
      gld16((const char*)Vt + ((size_t)(bh * DK + row)) * (S_LEN * 2) + (size_t)kv0 * 2 + scb,
            Vs + chunk * 1024);
    }
    __syncthreads();

    // S = Q K^T : rows=q (D layout), cols=key
    f32x4 sf[4] = {};
#pragma unroll
    for (int kk = 0; kk < 2; ++kk) {
      const bf16x8 a = kk ? qf1 : qf0;
#pragma unroll
      for (int j = 0; j < 4; ++j) {
        const int kr = j * 16 + l15;
        const bf16x8 bb = *reinterpret_cast<const bf16x8*>(
            Ks + kr * 128 + ((kk * 64 + 16 * lg) ^ ((kr & 7) << 4)));
        sf[j] = __builtin_amdgcn_mfma_f32_16x16x32_bf16(a, bb, sf[j], 0, 0, 0);
      }
    }

    if (t == nt - 1) {  // diagonal tile: causal mask (matches reference -1e9)
#pragma unroll
      for (int j = 0; j < 4; ++j) {
        const int key = kv0 + j * 16 + l15;
#pragma unroll
        for (int r = 0; r < 4; ++r) {
          const int qrow = q0 + wid * 16 + r4 + r;
          if (key > qrow) sf[j][r] = -1.0e9f;
        }
      }
    }

    // online softmax; row r lives in 16-lane group, cols spread over lanes+frags
#pragma unroll
    for (int r = 0; r < 4; ++r) {
      float mx = fmaxf(fmaxf(sf[0][r], sf[1][r]), fmaxf(sf[2][r], sf[3][r]));
      mx = fmaxf(mx, __shfl_xor(mx, 1));
      mx = fmaxf(mx, __shfl_xor(mx, 2));
      mx = fmaxf(mx, __shfl_xor(mx, 4));
      mx = fmaxf(mx, __shfl_xor(mx, 8));
      const float newm = fmaxf(m_r[r], mx);
      const float sc = __expf(m_r[r] - newm);
      m_r[r] = newm;
      float rs = 0.f;
#pragma unroll
      for (int j = 0; j < 4; ++j) {
        const float p = __expf(sf[j][r] - newm);
        sf[j][r] = p;
        rs += p;
      }
      rs += __shfl_xor(rs, 1);
      rs += __shfl_xor(rs, 2);
      rs += __shfl_xor(rs, 4);
      rs += __shfl_xor(rs, 8);
      l_r[r] = l_r[r] * sc + rs;
#pragma unroll
      for (int j = 0; j < 4; ++j) o[j][r] *= sc;
    }

    // P -> per-wave LDS (swizzled) to re-fragment as PV's A operand
    char* pw = Ps + wid * 2048;
#pragma unroll
    for (int r = 0; r < 4; ++r) {
      const int prow = r4 + r;
      const int sw = (prow & 7) << 4;
#pragma unroll
      for (int j = 0; j < 4; ++j)
        *reinterpret_cast<bf16*>(pw + prow * 128 + ((j * 32 + 2 * l15) ^ sw)) = (bf16)sf[j][r];
    }
    asm volatile("s_waitcnt lgkmcnt(0)" ::: "memory");  // per-wave LDS visibility

    // O += P V   (A=P rows=q, B=V cols=d from Vs[d][kv])
#pragma unroll
    for (int kk = 0; kk < 2; ++kk) {
      const bf16x8 pa = *reinterpret_cast<const bf16x8*>(
          pw + l15 * 128 + ((kk * 64 + 16 * lg) ^ ((l15 & 7) << 4)));
#pragma unroll
      for (int j = 0; j < 4; ++j) {
        const int vr = j * 16 + l15;
        const bf16x8 vb = *reinterpret_cast<const bf16x8*>(
            Vs + vr * 128 + ((kk * 64 + 16 * lg) ^ ((vr & 7) << 4)));
        o[j] = __builtin_amdgcn_mfma_f32_16x16x32_bf16(pa, vb, o[j], 0, 0, 0);
      }
    }
    __syncthreads();  // protect Ks/Vs before next tile's staging
  }

  // normalize + write attn output as [b][s][h*64+d] bf16 (A of out-proj GEMM)
  const int b = bh >> 4, h = bh & 15;
#pragma unroll
  for (int r = 0; r < 4; ++r) {
    const float inv = 1.0f / l_r[r];
    const int srow = q0 + wid * 16 + r4 + r;
    bf16* obase = O + ((size_t)(b * S_LEN + srow)) * DM + h * DK;
#pragma unroll
    for (int j = 0; j < 4; ++j) obase[j * 16 + l15] = (bf16)(o[j][r] * inv);
  }
}

// ---------------------------------------------------------------- out proj
__global__ __launch_bounds__(256) void gemm_out(
    const bf16* __restrict__ A, const bf16* __restrict__ W,
    const float* __restrict__ bias, float* __restrict__ C) {
  __shared__ char smem[32768];
  char* As = smem;
  char* Bs = smem + 16384;
  const int m0 = blockIdx.y * 128, n0 = blockIdx.x * 128;
  const int tid = threadIdx.x, lane = tid & 63, wid = tid >> 6;
  const int wr = (wid >> 1) * 64, wc = (wid & 1) * 64;
  const int scb = 16 * ((lane & 7) ^ (lane >> 3));
  const int lr8 = lane >> 3;
  f32x4 acc[4][4] = {};

  for (int k0 = 0; k0 < DM; k0 += 64) {
#pragma unroll
    for (int c = 0; c < 4; ++c) {
      const int chunk = wid * 4 + c;
      const int row = chunk * 8 + lr8;
      gld16((const char*)A + ((size_t)(m0 + row) * DM + k0) * 2 + scb, As + chunk * 1024);
      gld16((const char*)W + ((size_t)(n0 + row) * DM + k0) * 2 + scb, Bs + chunk * 1024);
    }
    __syncthreads();
#pragma unroll
    for (int kk = 0; kk < 2; ++kk) {
      bf16x8 af[4], bfr[4];
#pragma unroll
      for (int i = 0; i < 4; ++i) {
        const int ar = wr + i * 16 + (lane & 15);
        af[i] = *reinterpret_cast<const bf16x8*>(
            As + ar * 128 + ((kk * 64 + 16 * (lane >> 4)) ^ ((ar & 7) << 4)));
        const int br = wc + i * 16 + (lane & 15);
        bfr[i] = *reinterpret_cast<const bf16x8*>(
            Bs + br * 128 + ((kk * 64 + 16 * (lane >> 4)) ^ ((br & 7) << 4)));
      }
#pragma unroll
      for (int i = 0; i < 4; ++i)
#pragma unroll
        for (int j = 0; j < 4; ++j)
          acc[i][j] = __builtin_amdgcn_mfma_f32_16x16x32_bf16(af[i], bfr[j], acc[i][j], 0, 0, 0);
    }
    __syncthreads();
  }

  const int r4 = (lane >> 4) * 4;
#pragma unroll
  for (int i = 0; i < 4; ++i) {
    const int mrow = m0 + wr + i * 16 + r4;
#pragma unroll
    for (int j = 0; j < 4; ++j) {
      const int n = n0 + wc + j * 16 + (lane & 15);
      const float bs = bias[n];
#pragma unroll
      for (int r = 0; r < 4; ++r) C[(size_t)(mrow + r) * DM + n] = acc[i][j][r] + bs;
    }
  }
}

// ---------------------------------------------------------------- launcher
extern "C" void kernel_launch(void* const* d_in, const int* in_sizes, int n_in,
                              void* d_out, int out_size, void* d_ws, size_t ws_size,
                              hipStream_t stream) {
  const float* x = (const float*)d_in[0];
  // d_in[1] = causal mask (tril) — implemented analytically
  const float* Wq = (const float*)d_in[2];
  const float* bq = (const float*)d_in[3];
  const float* Wk = (const float*)d_in[4];
  const float* bk = (const float*)d_in[5];
  const float* Wv = (const float*)d_in[6];
  const float* bv = (const float*)d_in[7];
  const float* Wo = (const float*)d_in[8];
  const float* bo = (const float*)d_in[9];

  char* ws = (char*)d_ws;  // needs 48 MB
  bf16* xb  = (bf16*)(ws);                              // 8 MB  [4096][1024]
  bf16* wqb = (bf16*)(ws + (8u << 20));                 // 2 MB
  bf16* wkb = (bf16*)(ws + (10u << 20));                // 2 MB
  bf16* wvb = (bf16*)(ws + (12u << 20));                // 2 MB
  bf16* wob = (bf16*)(ws + (14u << 20));                // 2 MB
  bf16* Qw  = (bf16*)(ws + (16u << 20));                // 8 MB  [32][2048][64]
  bf16* Kw  = (bf16*)(ws + (24u << 20));                // 8 MB  [32][2048][64]
  bf16* Vtw = (bf16*)(ws + (32u << 20));                // 8 MB  [32][64][2048]
  bf16* AO  = (bf16*)(ws + (40u << 20));                // 8 MB  [4096][1024]

  cvt_f32_bf16_k<<<4096, 256, 0, stream>>>(x, xb, (MTOK * DM) / 4);
  cvt_f32_bf16_k<<<1024, 256, 0, stream>>>(Wq, wqb, (DM * DM) / 4);
  cvt_f32_bf16_k<<<1024, 256, 0, stream>>>(Wk, wkb, (DM * DM) / 4);
  cvt_f32_bf16_k<<<1024, 256, 0, stream>>>(Wv, wvb, (DM * DM) / 4);
  cvt_f32_bf16_k<<<1024, 256, 0, stream>>>(Wo, wob, (DM * DM) / 4);

  gemm_qkv<<<dim3(DM / 128, MTOK / 128, 3), 256, 0, stream>>>(
      xb, wqb, wkb, wvb, bq, bk, bv, Qw, Kw, Vtw);
  attn_fwd<<<dim3(S_LEN / 64, 32), 256, 0, stream>>>(Qw, Kw, Vtw, AO);
  gemm_out<<<dim3(DM / 128, MTOK / 128), 256, 0, stream>>>(AO, wob, bo, (float*)d_out);
}

// Round 3
// 173.636 us; speedup vs baseline: 1.1914x; 1.1914x over previous
//
#include <hip/hip_runtime.h>
#include <hip/hip_bf16.h>

typedef __bf16 bf16;
typedef bf16 bf16x8 __attribute__((ext_vector_type(8)));
typedef bf16 bf16x4 __attribute__((ext_vector_type(4)));
typedef float f32x4 __attribute__((ext_vector_type(4)));
typedef unsigned int u32;

#define S_LEN 2048
#define DM 1024
#define NH 16
#define DK 64
#define MTOK 4096  // B*S

// async global->LDS, 16B per lane; LDS dest is wave-uniform base + lane*16
__device__ __forceinline__ void gld16(const void* g, void* l) {
  __builtin_amdgcn_global_load_lds(
      (const __attribute__((address_space(1))) u32*)g,
      (__attribute__((address_space(3))) u32*)l, 16, 0, 0);
}

// ---------------------------------------------------------------- convert
// single fused launch: x (4M elems) + 4 weight matrices (1M each)
__global__ __launch_bounds__(256) void cvt_all(
    const float* __restrict__ x, const float* __restrict__ wq, const float* __restrict__ wk,
    const float* __restrict__ wv, const float* __restrict__ wo,
    bf16* __restrict__ xb, bf16* __restrict__ wqb, bf16* __restrict__ wkb,
    bf16* __restrict__ wvb, bf16* __restrict__ wob) {
  const int i = blockIdx.x * blockDim.x + threadIdx.x;
  const int NX = (MTOK * DM) / 4;  // 1048576 float4's
  const int NW = (DM * DM) / 4;    // 262144 float4's per weight
  const float* src;
  bf16* dst;
  int off;
  if (i < NX) {
    src = x; dst = xb; off = i;
  } else {
    const int j = i - NX;
    const int w = j >> 18;  // NW == 2^18
    off = j & (NW - 1);
    src = (w == 0) ? wq : (w == 1) ? wk : (w == 2) ? wv : wo;
    dst = (w == 0) ? wqb : (w == 1) ? wkb : (w == 2) ? wvb : wob;
  }
  f32x4 v = reinterpret_cast<const f32x4*>(src)[off];
  bf16x4 o;
  o[0] = (bf16)v[0]; o[1] = (bf16)v[1]; o[2] = (bf16)v[2]; o[3] = (bf16)v[3];
  reinterpret_cast<bf16x4*>(dst)[off] = o;
}

// ---------------------------------------------------------------- QKV GEMM
__global__ __launch_bounds__(256) void gemm_qkv(
    const bf16* __restrict__ A,
    const bf16* __restrict__ Wq, const bf16* __restrict__ Wk, const bf16* __restrict__ Wv,
    const float* __restrict__ Bq, const float* __restrict__ Bk, const float* __restrict__ Bv,
    bf16* __restrict__ Qo, bf16* __restrict__ Ko, bf16* __restrict__ Vt) {
  __shared__ char smem[32768];
  char* As = smem;
  char* Bs = smem + 16384;
  const int z = blockIdx.z;
  const bf16* W = (z == 0) ? Wq : (z == 1) ? Wk : Wv;
  const float* bias = (z == 0) ? Bq : (z == 1) ? Bk : Bv;
  const int m0 = blockIdx.y * 128;
  const int n0 = blockIdx.x * 128;
  const int tid = threadIdx.x;
  const int lane = tid & 63;
  const int wid = tid >> 6;
  const int wr = (wid >> 1) * 64, wc = (wid & 1) * 64;
  const int scb = 16 * ((lane & 7) ^ (lane >> 3));
  const int lr8 = lane >> 3;

  f32x4 acc[4][4] = {};

  for (int k0 = 0; k0 < DM; k0 += 64) {
#pragma unroll
    for (int c = 0; c < 4; ++c) {
      const int chunk = wid * 4 + c;
      const int row = chunk * 8 + lr8;
      gld16((const char*)A + ((size_t)(m0 + row) * DM + k0) * 2 + scb, As + chunk * 1024);
      gld16((const char*)W + ((size_t)(n0 + row) * DM + k0) * 2 + scb, Bs + chunk * 1024);
    }
    __syncthreads();
#pragma unroll
    for (int kk = 0; kk < 2; ++kk) {
      bf16x8 af[4], bfr[4];
#pragma unroll
      for (int i = 0; i < 4; ++i) {
        const int ar = wr + i * 16 + (lane & 15);
        af[i] = *reinterpret_cast<const bf16x8*>(
            As + ar * 128 + ((kk * 64 + 16 * (lane >> 4)) ^ ((ar & 7) << 4)));
        const int br = wc + i * 16 + (lane & 15);
        bfr[i] = *reinterpret_cast<const bf16x8*>(
            Bs + br * 128 + ((kk * 64 + 16 * (lane >> 4)) ^ ((br & 7) << 4)));
      }
#pragma unroll
      for (int i = 0; i < 4; ++i)
#pragma unroll
        for (int j = 0; j < 4; ++j)
          acc[i][j] = __builtin_amdgcn_mfma_f32_16x16x32_bf16(af[i], bfr[j], acc[i][j], 0, 0, 0);
    }
    __syncthreads();
  }

  const int bIdx = m0 >> 11;
  const int r4 = (lane >> 4) * 4;
#pragma unroll
  for (int i = 0; i < 4; ++i) {
    const int mrow = m0 + wr + i * 16 + r4;
    const int srow = mrow & (S_LEN - 1);
#pragma unroll
    for (int j = 0; j < 4; ++j) {
      const int n = n0 + wc + j * 16 + (lane & 15);
      const int h = n >> 6, d = n & 63;
      const int bh = bIdx * NH + h;
      const float bs = bias[n];
      if (z == 0) {
#pragma unroll
        for (int r = 0; r < 4; ++r)
          Qo[((size_t)bh * S_LEN + srow + r) * DK + d] = (bf16)((acc[i][j][r] + bs) * 0.125f);
      } else if (z == 1) {
#pragma unroll
        for (int r = 0; r < 4; ++r)
          Ko[((size_t)bh * S_LEN + srow + r) * DK + d] = (bf16)(acc[i][j][r] + bs);
      } else {
        bf16x4 pk;
#pragma unroll
        for (int r = 0; r < 4; ++r) pk[r] = (bf16)(acc[i][j][r] + bs);
        *reinterpret_cast<bf16x4*>(&Vt[((size_t)bh * DK + d) * S_LEN + srow]) = pk;
      }
    }
  }
}

// ---------------------------------------------------------------- attention
// QBLK=128 (4 waves x 32 rows), KVBLK=64, double-buffered K/V via
// global_load_lds with counted vmcnt(4), raw s_barrier (no full drain).
__global__ __launch_bounds__(256) void attn_fwd(
    const bf16* __restrict__ Q, const bf16* __restrict__ K,
    const bf16* __restrict__ Vt, bf16* __restrict__ O) {
  __shared__ char smem[49152];
  // layout: [0,16384) = K bufs (2 x 8192), [16384,32768) = V bufs (2 x 8192),
  //         [32768,49152) = per-wave P (4 x 4096)

  const int bid = blockIdx.x;
  const int qt = (S_LEN / 128 - 1) - (bid >> 5);  // heavy q-tiles first
  const int bh = bid & 31;
  const int tid = threadIdx.x, lane = tid & 63, wid = tid >> 6;
  const int q0 = qt * 128;
  const int scb = 16 * ((lane & 7) ^ (lane >> 3));
  const int l15 = lane & 15;
  const int lg = lane >> 4;
  const int r4 = lg * 4;

  // Q fragments (pre-scaled by 1/sqrt(dk) in gemm_qkv): rows q0+wid*32+mi*16+l15
  const bf16* qbase = Q + ((size_t)bh * S_LEN + q0 + wid * 32) * DK;
  bf16x8 qf[2][2];
#pragma unroll
  for (int mi = 0; mi < 2; ++mi)
#pragma unroll
    for (int kk = 0; kk < 2; ++kk)
      qf[mi][kk] = *reinterpret_cast<const bf16x8*>(
          qbase + (mi * 16 + l15) * DK + kk * 32 + 8 * lg);

  f32x4 o[2][4] = {};
  float m_r[2][4], l_r[2][4];
#pragma unroll
  for (int mi = 0; mi < 2; ++mi)
#pragma unroll
    for (int r = 0; r < 4; ++r) { m_r[mi][r] = -3.0e38f; l_r[mi][r] = 0.f; }

  const int nt = 2 * (qt + 1);

  auto STAGE = [&](int bi, int t) {
    const int kv0 = t * 64;
#pragma unroll
    for (int c = 0; c < 2; ++c) {
      const int chunk = wid * 2 + c;  // 8 chunks of 1KB (8 rows each)
      const int row = chunk * 8 + (lane >> 3);
      gld16((const char*)K + ((size_t)(bh * S_LEN + kv0 + row)) * 128 + scb,
            smem + bi * 8192 + chunk * 1024);
      gld16((const char*)Vt + ((size_t)(bh * DK + row)) * (S_LEN * 2) + (size_t)kv0 * 2 + scb,
            smem + 16384 + bi * 8192 + chunk * 1024);
    }
  };

  STAGE(0, 0);
  int cur = 0;
  char* pw = smem + 32768 + wid * 4096;

  for (int t = 0; t < nt; ++t) {
    const int kv0 = t * 64;
    if (t + 1 < nt) {
      STAGE(cur ^ 1, t + 1);
      asm volatile("s_waitcnt vmcnt(4)" ::: "memory");  // tile t resident, t+1 in flight
    } else {
      asm volatile("s_waitcnt vmcnt(0)" ::: "memory");
    }
    __builtin_amdgcn_s_barrier();
    asm volatile("" ::: "memory");
    const char* Kc = smem + cur * 8192;
    const char* Vc = smem + 16384 + cur * 8192;

    // ---- S = Q K^T
    f32x4 sf[2][4] = {};
#pragma unroll
    for (int kk = 0; kk < 2; ++kk) {
      bf16x8 bb[4];
#pragma unroll
      for (int j = 0; j < 4; ++j) {
        const int kr = j * 16 + l15;
        bb[j] = *reinterpret_cast<const bf16x8*>(
            Kc + kr * 128 + ((kk * 64 + 16 * lg) ^ ((kr & 7) << 4)));
      }
      __builtin_amdgcn_s_setprio(1);
#pragma unroll
      for (int mi = 0; mi < 2; ++mi)
#pragma unroll
        for (int j = 0; j < 4; ++j)
          sf[mi][j] = __builtin_amdgcn_mfma_f32_16x16x32_bf16(qf[mi][kk], bb[j], sf[mi][j], 0, 0, 0);
      __builtin_amdgcn_s_setprio(0);
    }

    if (t >= nt - 2) {  // diagonal region: causal mask (-1e9 like reference)
#pragma unroll
      for (int mi = 0; mi < 2; ++mi)
#pragma unroll
        for (int j = 0; j < 4; ++j) {
          const int key = kv0 + j * 16 + l15;
#pragma unroll
          for (int r = 0; r < 4; ++r) {
            const int qrow = q0 + wid * 32 + mi * 16 + r4 + r;
            if (key > qrow) sf[mi][j][r] = -1.0e9f;
          }
        }
    }

    // ---- online softmax (16-lane-group row reduce)
#pragma unroll
    for (int mi = 0; mi < 2; ++mi)
#pragma unroll
      for (int r = 0; r < 4; ++r) {
        float mx = fmaxf(fmaxf(sf[mi][0][r], sf[mi][1][r]), fmaxf(sf[mi][2][r], sf[mi][3][r]));
        mx = fmaxf(mx, __shfl_xor(mx, 1));
        mx = fmaxf(mx, __shfl_xor(mx, 2));
        mx = fmaxf(mx, __shfl_xor(mx, 4));
        mx = fmaxf(mx, __shfl_xor(mx, 8));
        const float newm = fmaxf(m_r[mi][r], mx);
        const float sc = __expf(m_r[mi][r] - newm);
        m_r[mi][r] = newm;
        float rs = 0.f;
#pragma unroll
        for (int j = 0; j < 4; ++j) {
          const float p = __expf(sf[mi][j][r] - newm);
          sf[mi][j][r] = p;
          rs += p;
        }
        rs += __shfl_xor(rs, 1);
        rs += __shfl_xor(rs, 2);
        rs += __shfl_xor(rs, 4);
        rs += __shfl_xor(rs, 8);
        l_r[mi][r] = l_r[mi][r] * sc + rs;
#pragma unroll
        for (int j = 0; j < 4; ++j) o[mi][j][r] *= sc;
      }

    // ---- P -> per-wave LDS (swizzled), re-fragment as PV A-operand
#pragma unroll
    for (int mi = 0; mi < 2; ++mi)
#pragma unroll
      for (int r = 0; r < 4; ++r) {
        const int pr = mi * 16 + r4 + r;
        const int sw = (pr & 7) << 4;
#pragma unroll
        for (int j = 0; j < 4; ++j)
          *reinterpret_cast<bf16*>(pw + pr * 128 + ((j * 32 + 2 * l15) ^ sw)) =
              (bf16)sf[mi][j][r];
      }

    // ---- O += P V
#pragma unroll
    for (int kk = 0; kk < 2; ++kk) {
      bf16x8 vb[4];
#pragma unroll
      for (int j = 0; j < 4; ++j) {
        const int vr = j * 16 + l15;
        vb[j] = *reinterpret_cast<const bf16x8*>(
            Vc + vr * 128 + ((kk * 64 + 16 * lg) ^ ((vr & 7) << 4)));
      }
      bf16x8 pa[2];
#pragma unroll
      for (int mi = 0; mi < 2; ++mi)
        pa[mi] = *reinterpret_cast<const bf16x8*>(
            pw + (mi * 16 + l15) * 128 + ((kk * 64 + 16 * lg) ^ ((l15 & 7) << 4)));
      __builtin_amdgcn_s_setprio(1);
#pragma unroll
      for (int mi = 0; mi < 2; ++mi)
#pragma unroll
        for (int j = 0; j < 4; ++j)
          o[mi][j] = __builtin_amdgcn_mfma_f32_16x16x32_bf16(pa[mi], vb[j], o[mi][j], 0, 0, 0);
      __builtin_amdgcn_s_setprio(0);
    }

    asm volatile("" ::: "memory");
    __builtin_amdgcn_s_barrier();  // all waves done with buf cur before overwrite
    cur ^= 1;
  }

  // ---- normalize + write [b][s][h*64+d]
  const int b = bh >> 4, h = bh & 15;
#pragma unroll
  for (int mi = 0; mi < 2; ++mi)
#pragma unroll
    for (int r = 0; r < 4; ++r) {
      const float inv = 1.0f / l_r[mi][r];
      const int srow = q0 + wid * 32 + mi * 16 + r4 + r;
      bf16* obase = O + ((size_t)(b * S_LEN + srow)) * DM + h * DK;
#pragma unroll
      for (int j = 0; j < 4; ++j) obase[j * 16 + l15] = (bf16)(o[mi][j][r] * inv);
    }
}

// ---------------------------------------------------------------- out proj
__global__ __launch_bounds__(256) void gemm_out(
    const bf16* __restrict__ A, const bf16* __restrict__ W,
    const float* __restrict__ bias, float* __restrict__ C) {
  __shared__ char smem[32768];
  char* As = smem;
  char* Bs = smem + 16384;
  const int m0 = blockIdx.y * 128, n0 = blockIdx.x * 128;
  const int tid = threadIdx.x, lane = tid & 63, wid = tid >> 6;
  const int wr = (wid >> 1) * 64, wc = (wid & 1) * 64;
  const int scb = 16 * ((lane & 7) ^ (lane >> 3));
  const int lr8 = lane >> 3;
  f32x4 acc[4][4] = {};

  for (int k0 = 0; k0 < DM; k0 += 64) {
#pragma unroll
    for (int c = 0; c < 4; ++c) {
      const int chunk = wid * 4 + c;
      const int row = chunk * 8 + lr8;
      gld16((const char*)A + ((size_t)(m0 + row) * DM + k0) * 2 + scb, As + chunk * 1024);
      gld16((const char*)W + ((size_t)(n0 + row) * DM + k0) * 2 + scb, Bs + chunk * 1024);
    }
    __syncthreads();
#pragma unroll
    for (int kk = 0; kk < 2; ++kk) {
      bf16x8 af[4], bfr[4];
#pragma unroll
      for (int i = 0; i < 4; ++i) {
        const int ar = wr + i * 16 + (lane & 15);
        af[i] = *reinterpret_cast<const bf16x8*>(
            As + ar * 128 + ((kk * 64 + 16 * (lane >> 4)) ^ ((ar & 7) << 4)));
        const int br = wc + i * 16 + (lane & 15);
        bfr[i] = *reinterpret_cast<const bf16x8*>(
            Bs + br * 128 + ((kk * 64 + 16 * (lane >> 4)) ^ ((br & 7) << 4)));
      }
#pragma unroll
      for (int i = 0; i < 4; ++i)
#pragma unroll
        for (int j = 0; j < 4; ++j)
          acc[i][j] = __builtin_amdgcn_mfma_f32_16x16x32_bf16(af[i], bfr[j], acc[i][j], 0, 0, 0);
    }
    __syncthreads();
  }

  const int r4 = (lane >> 4) * 4;
#pragma unroll
  for (int i = 0; i < 4; ++i) {
    const int mrow = m0 + wr + i * 16 + r4;
#pragma unroll
    for (int j = 0; j < 4; ++j) {
      const int n = n0 + wc + j * 16 + (lane & 15);
      const float bs = bias[n];
#pragma unroll
      for (int r = 0; r < 4; ++r) C[(size_t)(mrow + r) * DM + n] = acc[i][j][r] + bs;
    }
  }
}

// ---------------------------------------------------------------- launcher
extern "C" void kernel_launch(void* const* d_in, const int* in_sizes, int n_in,
                              void* d_out, int out_size, void* d_ws, size_t ws_size,
                              hipStream_t stream) {
  const float* x = (const float*)d_in[0];
  const float* Wq = (const float*)d_in[2];
  const float* bq = (const float*)d_in[3];
  const float* Wk = (const float*)d_in[4];
  const float* bk = (const float*)d_in[5];
  const float* Wv = (const float*)d_in[6];
  const float* bv = (const float*)d_in[7];
  const float* Wo = (const float*)d_in[8];
  const float* bo = (const float*)d_in[9];

  char* ws = (char*)d_ws;  // needs 48 MB
  bf16* xb  = (bf16*)(ws);
  bf16* wqb = (bf16*)(ws + (8u << 20));
  bf16* wkb = (bf16*)(ws + (10u << 20));
  bf16* wvb = (bf16*)(ws + (12u << 20));
  bf16* wob = (bf16*)(ws + (14u << 20));
  bf16* Qw  = (bf16*)(ws + (16u << 20));
  bf16* Kw  = (bf16*)(ws + (24u << 20));
  bf16* Vtw = (bf16*)(ws + (32u << 20));
  bf16* AO  = (bf16*)(ws + (40u << 20));

  cvt_all<<<8192, 256, 0, stream>>>(x, Wq, Wk, Wv, Wo, xb, wqb, wkb, wvb, wob);

  gemm_qkv<<<dim3(DM / 128, MTOK / 128, 3), 256, 0, stream>>>(
      xb, wqb, wkb, wvb, bq, bk, bv, Qw, Kw, Vtw);
  attn_fwd<<<dim3((S_LEN / 128) * 32), 256, 0, stream>>>(Qw, Kw, Vtw, AO);
  gemm_out<<<dim3(DM / 128, MTOK / 128), 256, 0, stream>>>(AO, wob, bo, (float*)d_out);
}

// Round 4
// 149.400 us; speedup vs baseline: 1.3846x; 1.1622x over previous
//
#include <hip/hip_runtime.h>
#include <hip/hip_bf16.h>

typedef __bf16 bf16;
typedef bf16 bf16x8 __attribute__((ext_vector_type(8)));
typedef bf16 bf16x4 __attribute__((ext_vector_type(4)));
typedef float f32x4 __attribute__((ext_vector_type(4)));
typedef unsigned int u32;

#define S_LEN 2048
#define DM 1024
#define NH 16
#define DK 64
#define MTOK 4096  // B*S

// async global->LDS, 16B per lane; LDS dest is wave-uniform base + lane*16
__device__ __forceinline__ void gld16(const void* g, void* l) {
  __builtin_amdgcn_global_load_lds(
      (const __attribute__((address_space(1))) u32*)g,
      (__attribute__((address_space(3))) u32*)l, 16, 0, 0);
}

// ---------------------------------------------------------------- convert
__global__ __launch_bounds__(256) void cvt_all(
    const float* __restrict__ x, const float* __restrict__ wq, const float* __restrict__ wk,
    const float* __restrict__ wv, const float* __restrict__ wo,
    bf16* __restrict__ xb, bf16* __restrict__ wqb, bf16* __restrict__ wkb,
    bf16* __restrict__ wvb, bf16* __restrict__ wob) {
  const int i = blockIdx.x * blockDim.x + threadIdx.x;
  const int NX = (MTOK * DM) / 4;
  const int NW = (DM * DM) / 4;
  const float* src;
  bf16* dst;
  int off;
  if (i < NX) {
    src = x; dst = xb; off = i;
  } else {
    const int j = i - NX;
    const int w = j >> 18;
    off = j & (NW - 1);
    src = (w == 0) ? wq : (w == 1) ? wk : (w == 2) ? wv : wo;
    dst = (w == 0) ? wqb : (w == 1) ? wkb : (w == 2) ? wvb : wob;
  }
  f32x4 v = reinterpret_cast<const f32x4*>(src)[off];
  bf16x4 o;
  o[0] = (bf16)v[0]; o[1] = (bf16)v[1]; o[2] = (bf16)v[2]; o[3] = (bf16)v[3];
  reinterpret_cast<bf16x4*>(dst)[off] = o;
}

// ---------------------------------------------------------------- QKV GEMM
__global__ __launch_bounds__(256) void gemm_qkv(
    const bf16* __restrict__ A,
    const bf16* __restrict__ Wq, const bf16* __restrict__ Wk, const bf16* __restrict__ Wv,
    const float* __restrict__ Bq, const float* __restrict__ Bk, const float* __restrict__ Bv,
    bf16* __restrict__ Qo, bf16* __restrict__ Ko, bf16* __restrict__ Vt) {
  __shared__ char smem[32768];
  char* As = smem;
  char* Bs = smem + 16384;
  const int z = blockIdx.z;
  const bf16* W = (z == 0) ? Wq : (z == 1) ? Wk : Wv;
  const float* bias = (z == 0) ? Bq : (z == 1) ? Bk : Bv;
  const int m0 = blockIdx.y * 128;
  const int n0 = blockIdx.x * 128;
  const int tid = threadIdx.x;
  const int lane = tid & 63;
  const int wid = tid >> 6;
  const int wr = (wid >> 1) * 64, wc = (wid & 1) * 64;
  const int scb = 16 * ((lane & 7) ^ (lane >> 3));
  const int lr8 = lane >> 3;

  f32x4 acc[4][4] = {};

  for (int k0 = 0; k0 < DM; k0 += 64) {
#pragma unroll
    for (int c = 0; c < 4; ++c) {
      const int chunk = wid * 4 + c;
      const int row = chunk * 8 + lr8;
      gld16((const char*)A + ((size_t)(m0 + row) * DM + k0) * 2 + scb, As + chunk * 1024);
      gld16((const char*)W + ((size_t)(n0 + row) * DM + k0) * 2 + scb, Bs + chunk * 1024);
    }
    __syncthreads();
#pragma unroll
    for (int kk = 0; kk < 2; ++kk) {
      bf16x8 af[4], bfr[4];
#pragma unroll
      for (int i = 0; i < 4; ++i) {
        const int ar = wr + i * 16 + (lane & 15);
        af[i] = *reinterpret_cast<const bf16x8*>(
            As + ar * 128 + ((kk * 64 + 16 * (lane >> 4)) ^ ((ar & 7) << 4)));
        const int br = wc + i * 16 + (lane & 15);
        bfr[i] = *reinterpret_cast<const bf16x8*>(
            Bs + br * 128 + ((kk * 64 + 16 * (lane >> 4)) ^ ((br & 7) << 4)));
      }
#pragma unroll
      for (int i = 0; i < 4; ++i)
#pragma unroll
        for (int j = 0; j < 4; ++j)
          acc[i][j] = __builtin_amdgcn_mfma_f32_16x16x32_bf16(af[i], bfr[j], acc[i][j], 0, 0, 0);
    }
    __syncthreads();
  }

  const int bIdx = m0 >> 11;
  const int r4 = (lane >> 4) * 4;
#pragma unroll
  for (int i = 0; i < 4; ++i) {
    const int mrow = m0 + wr + i * 16 + r4;
    const int srow = mrow & (S_LEN - 1);
#pragma unroll
    for (int j = 0; j < 4; ++j) {
      const int n = n0 + wc + j * 16 + (lane & 15);
      const int h = n >> 6, d = n & 63;
      const int bh = bIdx * NH + h;
      const float bs = bias[n];
      if (z == 0) {
#pragma unroll
        for (int r = 0; r < 4; ++r)
          Qo[((size_t)bh * S_LEN + srow + r) * DK + d] = (bf16)((acc[i][j][r] + bs) * 0.125f);
      } else if (z == 1) {
#pragma unroll
        for (int r = 0; r < 4; ++r)
          Ko[((size_t)bh * S_LEN + srow + r) * DK + d] = (bf16)(acc[i][j][r] + bs);
      } else {
        bf16x4 pk;
#pragma unroll
        for (int r = 0; r < 4; ++r) pk[r] = (bf16)(acc[i][j][r] + bs);
        *reinterpret_cast<bf16x4*>(&Vt[((size_t)bh * DK + d) * S_LEN + srow]) = pk;
      }
    }
  }
}

// ---------------------------------------------------------------- attention
// QBLK=128, 8 waves x 16 rows (512 threads) -> 4 waves/SIMD for phase overlap.
// KVBLK=64 double-buffered via global_load_lds, counted vmcnt(2), raw s_barrier.
__global__ __launch_bounds__(512) void attn_fwd(
    const bf16* __restrict__ Q, const bf16* __restrict__ K,
    const bf16* __restrict__ Vt, bf16* __restrict__ O) {
  __shared__ char smem[49152];
  // [0,16384) K bufs (2 x 8192); [16384,32768) V bufs (2 x 8192);
  // [32768,49152) per-wave P (8 x 2048)

  const int bid = blockIdx.x;
  const int qt = (S_LEN / 128 - 1) - (bid >> 5);  // heavy q-tiles first
  const int bh = bid & 31;
  const int tid = threadIdx.x, lane = tid & 63, wid = tid >> 6;
  const int q0 = qt * 128;
  const int scb = 16 * ((lane & 7) ^ (lane >> 3));
  const int l15 = lane & 15;
  const int lg = lane >> 4;
  const int r4 = lg * 4;

  // Q fragments (pre-scaled by 1/sqrt(dk)): wave rows q0+wid*16 .. +15
  const bf16* qbase = Q + ((size_t)bh * S_LEN + q0 + wid * 16) * DK;
  bf16x8 qf[2];
#pragma unroll
  for (int kk = 0; kk < 2; ++kk)
    qf[kk] = *reinterpret_cast<const bf16x8*>(qbase + l15 * DK + kk * 32 + 8 * lg);

  f32x4 o[4] = {};
  float m_r[4], l_r[4];
#pragma unroll
  for (int r = 0; r < 4; ++r) { m_r[r] = -3.0e38f; l_r[r] = 0.f; }

  const int nt = 2 * (qt + 1);

  auto STAGE = [&](int bi, int t) {
    const int kv0 = t * 64;
    const int row = wid * 8 + (lane >> 3);  // 64 rows over 8 waves
    gld16((const char*)K + ((size_t)(bh * S_LEN + kv0 + row)) * 128 + scb,
          smem + bi * 8192 + wid * 1024);
    gld16((const char*)Vt + ((size_t)(bh * DK + row)) * (S_LEN * 2) + (size_t)kv0 * 2 + scb,
          smem + 16384 + bi * 8192 + wid * 1024);
  };

  STAGE(0, 0);
  int cur = 0;
  char* pw = smem + 32768 + wid * 2048;

  for (int t = 0; t < nt; ++t) {
    const int kv0 = t * 64;
    if (t + 1 < nt) {
      STAGE(cur ^ 1, t + 1);
      asm volatile("s_waitcnt vmcnt(2)" ::: "memory");  // tile t resident, t+1 in flight
    } else {
      asm volatile("s_waitcnt vmcnt(0)" ::: "memory");
    }
    __builtin_amdgcn_s_barrier();
    asm volatile("" ::: "memory");
    const char* Kc = smem + cur * 8192;
    const char* Vc = smem + 16384 + cur * 8192;

    // ---- S = Q K^T
    f32x4 sf[4] = {};
#pragma unroll
    for (int kk = 0; kk < 2; ++kk) {
      bf16x8 bb[4];
#pragma unroll
      for (int j = 0; j < 4; ++j) {
        const int kr = j * 16 + l15;
        bb[j] = *reinterpret_cast<const bf16x8*>(
            Kc + kr * 128 + ((kk * 64 + 16 * lg) ^ ((kr & 7) << 4)));
      }
      __builtin_amdgcn_s_setprio(1);
#pragma unroll
      for (int j = 0; j < 4; ++j)
        sf[j] = __builtin_amdgcn_mfma_f32_16x16x32_bf16(qf[kk], bb[j], sf[j], 0, 0, 0);
      __builtin_amdgcn_s_setprio(0);
    }

    if (t >= nt - 2) {  // diagonal region: causal mask (-1e9 like reference)
#pragma unroll
      for (int j = 0; j < 4; ++j) {
        const int key = kv0 + j * 16 + l15;
#pragma unroll
        for (int r = 0; r < 4; ++r) {
          const int qrow = q0 + wid * 16 + r4 + r;
          if (key > qrow) sf[j][r] = -1.0e9f;
        }
      }
    }

    // ---- online softmax (16-lane-group row reduce), 4 rows per lane
#pragma unroll
    for (int r = 0; r < 4; ++r) {
      float mx = fmaxf(fmaxf(sf[0][r], sf[1][r]), fmaxf(sf[2][r], sf[3][r]));
      mx = fmaxf(mx, __shfl_xor(mx, 1));
      mx = fmaxf(mx, __shfl_xor(mx, 2));
      mx = fmaxf(mx, __shfl_xor(mx, 4));
      mx = fmaxf(mx, __shfl_xor(mx, 8));
      const float newm = fmaxf(m_r[r], mx);
      const float sc = __expf(m_r[r] - newm);
      m_r[r] = newm;
      float rs = 0.f;
#pragma unroll
      for (int j = 0; j < 4; ++j) {
        const float p = __expf(sf[j][r] - newm);
        sf[j][r] = p;
        rs += p;
      }
      rs += __shfl_xor(rs, 1);
      rs += __shfl_xor(rs, 2);
      rs += __shfl_xor(rs, 4);
      rs += __shfl_xor(rs, 8);
      l_r[r] = l_r[r] * sc + rs;
#pragma unroll
      for (int j = 0; j < 4; ++j) o[j][r] *= sc;
    }

    // ---- P -> per-wave LDS (swizzled), re-fragment as PV A-operand
#pragma unroll
    for (int r = 0; r < 4; ++r) {
      const int pr = r4 + r;
      const int sw = (pr & 7) << 4;
#pragma unroll
      for (int j = 0; j < 4; ++j)
        *reinterpret_cast<bf16*>(pw + pr * 128 + ((j * 32 + 2 * l15) ^ sw)) = (bf16)sf[j][r];
    }

    // ---- O += P V
#pragma unroll
    for (int kk = 0; kk < 2; ++kk) {
      bf16x8 vb[4];
#pragma unroll
      for (int j = 0; j < 4; ++j) {
        const int vr = j * 16 + l15;
        vb[j] = *reinterpret_cast<const bf16x8*>(
            Vc + vr * 128 + ((kk * 64 + 16 * lg) ^ ((vr & 7) << 4)));
      }
      const bf16x8 pa = *reinterpret_cast<const bf16x8*>(
          pw + l15 * 128 + ((kk * 64 + 16 * lg) ^ ((l15 & 7) << 4)));
      __builtin_amdgcn_s_setprio(1);
#pragma unroll
      for (int j = 0; j < 4; ++j)
        o[j] = __builtin_amdgcn_mfma_f32_16x16x32_bf16(pa, vb[j], o[j], 0, 0, 0);
      __builtin_amdgcn_s_setprio(0);
    }

    asm volatile("" ::: "memory");
    __builtin_amdgcn_s_barrier();  // all waves done with buf cur before overwrite
    cur ^= 1;
  }

  // ---- normalize + write [b][s][h*64+d]
  const int b = bh >> 4, h = bh & 15;
#pragma unroll
  for (int r = 0; r < 4; ++r) {
    const float inv = 1.0f / l_r[r];
    const int srow = q0 + wid * 16 + r4 + r;
    bf16* obase = O + ((size_t)(b * S_LEN + srow)) * DM + h * DK;
#pragma unroll
    for (int j = 0; j < 4; ++j) obase[j * 16 + l15] = (bf16)(o[j][r] * inv);
  }
}

// ---------------------------------------------------------------- out proj
__global__ __launch_bounds__(256) void gemm_out(
    const bf16* __restrict__ A, const bf16* __restrict__ W,
    const float* __restrict__ bias, float* __restrict__ C) {
  __shared__ char smem[32768];
  char* As = smem;
  char* Bs = smem + 16384;
  const int m0 = blockIdx.y * 128, n0 = blockIdx.x * 128;
  const int tid = threadIdx.x, lane = tid & 63, wid = tid >> 6;
  const int wr = (wid >> 1) * 64, wc = (wid & 1) * 64;
  const int scb = 16 * ((lane & 7) ^ (lane >> 3));
  const int lr8 = lane >> 3;
  f32x4 acc[4][4] = {};

  for (int k0 = 0; k0 < DM; k0 += 64) {
#pragma unroll
    for (int c = 0; c < 4; ++c) {
      const int chunk = wid * 4 + c;
      const int row = chunk * 8 + lr8;
      gld16((const char*)A + ((size_t)(m0 + row) * DM + k0) * 2 + scb, As + chunk * 1024);
      gld16((const char*)W + ((size_t)(n0 + row) * DM + k0) * 2 + scb, Bs + chunk * 1024);
    }
    __syncthreads();
#pragma unroll
    for (int kk = 0; kk < 2; ++kk) {
      bf16x8 af[4], bfr[4];
#pragma unroll
      for (int i = 0; i < 4; ++i) {
        const int ar = wr + i * 16 + (lane & 15);
        af[i] = *reinterpret_cast<const bf16x8*>(
            As + ar * 128 + ((kk * 64 + 16 * (lane >> 4)) ^ ((ar & 7) << 4)));
        const int br = wc + i * 16 + (lane & 15);
        bfr[i] = *reinterpret_cast<const bf16x8*>(
            Bs + br * 128 + ((kk * 64 + 16 * (lane >> 4)) ^ ((br & 7) << 4)));
      }
#pragma unroll
      for (int i = 0; i < 4; ++i)
#pragma unroll
        for (int j = 0; j < 4; ++j)
          acc[i][j] = __builtin_amdgcn_mfma_f32_16x16x32_bf16(af[i], bfr[j], acc[i][j], 0, 0, 0);
    }
    __syncthreads();
  }

  const int r4 = (lane >> 4) * 4;
#pragma unroll
  for (int i = 0; i < 4; ++i) {
    const int mrow = m0 + wr + i * 16 + r4;
#pragma unroll
    for (int j = 0; j < 4; ++j) {
      const int n = n0 + wc + j * 16 + (lane & 15);
      const float bs = bias[n];
#pragma unroll
      for (int r = 0; r < 4; ++r) C[(size_t)(mrow + r) * DM + n] = acc[i][j][r] + bs;
    }
  }
}

// ---------------------------------------------------------------- launcher
extern "C" void kernel_launch(void* const* d_in, const int* in_sizes, int n_in,
                              void* d_out, int out_size, void* d_ws, size_t ws_size,
                              hipStream_t stream) {
  const float* x = (const float*)d_in[0];
  const float* Wq = (const float*)d_in[2];
  const float* bq = (const float*)d_in[3];
  const float* Wk = (const float*)d_in[4];
  const float* bk = (const float*)d_in[5];
  const float* Wv = (const float*)d_in[6];
  const float* bv = (const float*)d_in[7];
  const float* Wo = (const float*)d_in[8];
  const float* bo = (const float*)d_in[9];

  char* ws = (char*)d_ws;  // needs 48 MB
  bf16* xb  = (bf16*)(ws);
  bf16* wqb = (bf16*)(ws + (8u << 20));
  bf16* wkb = (bf16*)(ws + (10u << 20));
  bf16* wvb = (bf16*)(ws + (12u << 20));
  bf16* wob = (bf16*)(ws + (14u << 20));
  bf16* Qw  = (bf16*)(ws + (16u << 20));
  bf16* Kw  = (bf16*)(ws + (24u << 20));
  bf16* Vtw = (bf16*)(ws + (32u << 20));
  bf16* AO  = (bf16*)(ws + (40u << 20));

  cvt_all<<<8192, 256, 0, stream>>>(x, Wq, Wk, Wv, Wo, xb, wqb, wkb, wvb, wob);

  gemm_qkv<<<dim3(DM / 128, MTOK / 128, 3), 256, 0, stream>>>(
      xb, wqb, wkb, wvb, bq, bk, bv, Qw, Kw, Vtw);
  attn_fwd<<<dim3((S_LEN / 128) * 32), 512, 0, stream>>>(Qw, Kw, Vtw, AO);
  gemm_out<<<dim3(DM / 128, MTOK / 128), 256, 0, stream>>>(AO, wob, bo, (float*)d_out);
}

// Round 6
// 136.695 us; speedup vs baseline: 1.5133x; 1.0929x over previous
//
#include <hip/hip_runtime.h>
#include <hip/hip_bf16.h>

typedef __bf16 bf16;
typedef bf16 bf16x8 __attribute__((ext_vector_type(8)));
typedef bf16 bf16x4 __attribute__((ext_vector_type(4)));
typedef float f32x4 __attribute__((ext_vector_type(4)));
typedef unsigned int u32;

#define S_LEN 2048
#define DM 1024
#define NH 16
#define DK 64
#define MTOK 4096  // B*S

// async global->LDS, 16B per lane; LDS dest is wave-uniform base + lane*16
__device__ __forceinline__ void gld16(const void* g, void* l) {
  __builtin_amdgcn_global_load_lds(
      (const __attribute__((address_space(1))) u32*)g,
      (__attribute__((address_space(3))) u32*)l, 16, 0, 0);
}

// ---------------------------------------------------------------- convert
__global__ __launch_bounds__(256) void cvt_all(
    const float* __restrict__ x, const float* __restrict__ wq, const float* __restrict__ wk,
    const float* __restrict__ wv, const float* __restrict__ wo,
    bf16* __restrict__ xb, bf16* __restrict__ wqb, bf16* __restrict__ wkb,
    bf16* __restrict__ wvb, bf16* __restrict__ wob) {
  const int i = blockIdx.x * blockDim.x + threadIdx.x;
  const int NX = (MTOK * DM) / 4;
  const int NW = (DM * DM) / 4;
  const float* src;
  bf16* dst;
  int off;
  if (i < NX) {
    src = x; dst = xb; off = i;
  } else {
    const int j = i - NX;
    const int w = j >> 18;
    off = j & (NW - 1);
    src = (w == 0) ? wq : (w == 1) ? wk : (w == 2) ? wv : wo;
    dst = (w == 0) ? wqb : (w == 1) ? wkb : (w == 2) ? wvb : wob;
  }
  f32x4 v = reinterpret_cast<const f32x4*>(src)[off];
  bf16x4 o;
  o[0] = (bf16)v[0]; o[1] = (bf16)v[1]; o[2] = (bf16)v[2]; o[3] = (bf16)v[3];
  reinterpret_cast<bf16x4*>(dst)[off] = o;
}

// ---------------------------------------------------------------- QKV GEMM
// 128x128 tile, BK=64. 2-phase double buffer: buf i at i*32768 (A 16KB + B 16KB).
// STAGE(next) at loop top; one vmcnt(0)+s_barrier per K-step (guide T3 minimum).
__global__ __launch_bounds__(256) void gemm_qkv(
    const bf16* __restrict__ A,
    const bf16* __restrict__ Wq, const bf16* __restrict__ Wk, const bf16* __restrict__ Wv,
    const float* __restrict__ Bq, const float* __restrict__ Bk, const float* __restrict__ Bv,
    bf16* __restrict__ Qo, bf16* __restrict__ Ko, bf16* __restrict__ Vt) {
  __shared__ char smem[65536];
  const int z = blockIdx.z;
  const bf16* W = (z == 0) ? Wq : (z == 1) ? Wk : Wv;
  const float* bias = (z == 0) ? Bq : (z == 1) ? Bk : Bv;
  const int m0 = blockIdx.y * 128;
  const int n0 = blockIdx.x * 128;
  const int tid = threadIdx.x;
  const int lane = tid & 63;
  const int wid = tid >> 6;
  const int wr = (wid >> 1) * 64, wc = (wid & 1) * 64;
  const int scb = 16 * ((lane & 7) ^ (lane >> 3));
  const int lr8 = lane >> 3;

  f32x4 acc[4][4] = {};

  auto STAGE = [&](int bi, int k0) {
#pragma unroll
    for (int c = 0; c < 4; ++c) {
      const int chunk = wid * 4 + c;  // 16 chunks x 1KB = 16KB per matrix
      const int row = chunk * 8 + lr8;
      gld16((const char*)A + ((size_t)(m0 + row) * DM + k0) * 2 + scb,
            smem + bi * 32768 + chunk * 1024);
      gld16((const char*)W + ((size_t)(n0 + row) * DM + k0) * 2 + scb,
            smem + bi * 32768 + 16384 + chunk * 1024);
    }
  };

  STAGE(0, 0);
  asm volatile("s_waitcnt vmcnt(0)" ::: "memory");
  __builtin_amdgcn_s_barrier();

  const int NK = DM / 64;  // 16
  for (int it = 0; it < NK; ++it) {
    if (it + 1 < NK) STAGE((it + 1) & 1, (it + 1) * 64);
    const char* As = smem + (it & 1) * 32768;
    const char* Bs = As + 16384;
#pragma unroll
    for (int kk = 0; kk < 2; ++kk) {
      bf16x8 af[4], bfr[4];
#pragma unroll
      for (int i = 0; i < 4; ++i) {
        const int ar = wr + i * 16 + (lane & 15);
        af[i] = *reinterpret_cast<const bf16x8*>(
            As + ar * 128 + ((kk * 64 + 16 * (lane >> 4)) ^ ((ar & 7) << 4)));
        const int br = wc + i * 16 + (lane & 15);
        bfr[i] = *reinterpret_cast<const bf16x8*>(
            Bs + br * 128 + ((kk * 64 + 16 * (lane >> 4)) ^ ((br & 7) << 4)));
      }
      __builtin_amdgcn_s_setprio(1);
#pragma unroll
      for (int i = 0; i < 4; ++i)
#pragma unroll
        for (int j = 0; j < 4; ++j)
          acc[i][j] = __builtin_amdgcn_mfma_f32_16x16x32_bf16(af[i], bfr[j], acc[i][j], 0, 0, 0);
      __builtin_amdgcn_s_setprio(0);
    }
    asm volatile("s_waitcnt vmcnt(0)" ::: "memory");
    __builtin_amdgcn_s_barrier();
  }

  // Q pre-scale: 1/sqrt(dk) * log2(e)  (attn softmax runs in exp2 domain)
  const float QSC = 0.125f * 1.44269504089f;
  const int bIdx = m0 >> 11;
  const int r4 = (lane >> 4) * 4;
#pragma unroll
  for (int i = 0; i < 4; ++i) {
    const int mrow = m0 + wr + i * 16 + r4;
    const int srow = mrow & (S_LEN - 1);
#pragma unroll
    for (int j = 0; j < 4; ++j) {
      const int n = n0 + wc + j * 16 + (lane & 15);
      const int h = n >> 6, d = n & 63;
      const int bh = bIdx * NH + h;
      const float bs = bias[n];
      if (z == 0) {
#pragma unroll
        for (int r = 0; r < 4; ++r)
          Qo[((size_t)bh * S_LEN + srow + r) * DK + d] = (bf16)((acc[i][j][r] + bs) * QSC);
      } else if (z == 1) {
#pragma unroll
        for (int r = 0; r < 4; ++r)
          Ko[((size_t)bh * S_LEN + srow + r) * DK + d] = (bf16)(acc[i][j][r] + bs);
      } else {
        bf16x4 pk;
#pragma unroll
        for (int r = 0; r < 4; ++r) pk[r] = (bf16)(acc[i][j][r] + bs);
        *reinterpret_cast<bf16x4*>(&Vt[((size_t)bh * DK + d) * S_LEN + srow]) = pk;
      }
    }
  }
}

// ---------------------------------------------------------------- attention
// QBLK=128, 8 waves x 16 rows. KVBLK=64, 3-buffer rotation, ONE barrier/tile,
// counted vmcnt(2). exp2-domain softmax with defer-max (THR=8).
__global__ __launch_bounds__(512) void attn_fwd(
    const bf16* __restrict__ Q, const bf16* __restrict__ K,
    const bf16* __restrict__ Vt, bf16* __restrict__ O) {
  __shared__ char smem[65536];
  // buf i (i<3): K at i*16384 (8KB), V at i*16384+8192 (8KB); P at 49152+wid*2048

  const int bid = blockIdx.x;
  const int qt = (S_LEN / 128 - 1) - (bid >> 5);  // heavy q-tiles first
  const int bh = bid & 31;
  const int tid = threadIdx.x, lane = tid & 63, wid = tid >> 6;
  const int q0 = qt * 128;
  const int scb = 16 * ((lane & 7) ^ (lane >> 3));
  const int l15 = lane & 15;
  const int lg = lane >> 4;
  const int r4 = lg * 4;

  // Q fragments (pre-scaled by 1/sqrt(dk)*log2e)
  const bf16* qbase = Q + ((size_t)bh * S_LEN + q0 + wid * 16) * DK;
  bf16x8 qf[2];
#pragma unroll
  for (int kk = 0; kk < 2; ++kk)
    qf[kk] = *reinterpret_cast<const bf16x8*>(qbase + l15 * DK + kk * 32 + 8 * lg);

  f32x4 o[4] = {};
  float m_r[4], l_r[4];
#pragma unroll
  for (int r = 0; r < 4; ++r) { m_r[r] = -3.0e38f; l_r[r] = 0.f; }

  const int nt = 2 * (qt + 1);

  auto STAGE = [&](int bi, int t) {
    const int kv0 = t * 64;
    const int row = wid * 8 + (lane >> 3);  // 64 rows over 8 waves
    gld16((const char*)K + ((size_t)(bh * S_LEN + kv0 + row)) * 128 + scb,
          smem + bi * 16384 + wid * 1024);
    gld16((const char*)Vt + ((size_t)(bh * DK + row)) * (S_LEN * 2) + (size_t)kv0 * 2 + scb,
          smem + bi * 16384 + 8192 + wid * 1024);
  };

  STAGE(0, 0);
  char* pw = smem + 49152 + wid * 2048;

  for (int t = 0; t < nt; ++t) {
    const int kv0 = t * 64;
    if (t + 1 < nt) {
      STAGE((t + 1) % 3, t + 1);
      asm volatile("s_waitcnt vmcnt(2)" ::: "memory");  // tile t resident, t+1 in flight
    } else {
      asm volatile("s_waitcnt vmcnt(0)" ::: "memory");
    }
    __builtin_amdgcn_s_barrier();
    asm volatile("" ::: "memory");
    const char* Kc = smem + (t % 3) * 16384;
    const char* Vc = Kc + 8192;

    // ---- S = Q K^T (exp2 domain)
    f32x4 sf[4] = {};
#pragma unroll
    for (int kk = 0; kk < 2; ++kk) {
      bf16x8 bb[4];
#pragma unroll
      for (int j = 0; j < 4; ++j) {
        const int kr = j * 16 + l15;
        bb[j] = *reinterpret_cast<const bf16x8*>(
            Kc + kr * 128 + ((kk * 64 + 16 * lg) ^ ((kr & 7) << 4)));
      }
      __builtin_amdgcn_s_setprio(1);
#pragma unroll
      for (int j = 0; j < 4; ++j)
        sf[j] = __builtin_amdgcn_mfma_f32_16x16x32_bf16(qf[kk], bb[j], sf[j], 0, 0, 0);
      __builtin_amdgcn_s_setprio(0);
    }

    if (t >= nt - 2) {  // diagonal region: causal mask
#pragma unroll
      for (int j = 0; j < 4; ++j) {
        const int key = kv0 + j * 16 + l15;
#pragma unroll
        for (int r = 0; r < 4; ++r) {
          const int qrow = q0 + wid * 16 + r4 + r;
          if (key > qrow) sf[j][r] = -1.0e9f;
        }
      }
    }

    // ---- online softmax (exp2 domain, defer-max THR=8)
#pragma unroll
    for (int r = 0; r < 4; ++r) {
      float mx = fmaxf(fmaxf(sf[0][r], sf[1][r]), fmaxf(sf[2][r], sf[3][r]));
      mx = fmaxf(mx, __shfl_xor(mx, 1));
      mx = fmaxf(mx, __shfl_xor(mx, 2));
      mx = fmaxf(mx, __shfl_xor(mx, 4));
      mx = fmaxf(mx, __shfl_xor(mx, 8));
      if (mx > m_r[r] + 8.f) {  // rescale only on significant growth
        const float sc = exp2f(m_r[r] - mx);
        l_r[r] *= sc;
#pragma unroll
        for (int j = 0; j < 4; ++j) o[j][r] *= sc;
        m_r[r] = mx;
      }
      const float m_new = m_r[r];
      float rs = 0.f;
#pragma unroll
      for (int j = 0; j < 4; ++j) {
        const float p = exp2f(sf[j][r] - m_new);
        sf[j][r] = p;
        rs += p;
      }
      rs += __shfl_xor(rs, 1);
      rs += __shfl_xor(rs, 2);
      rs += __shfl_xor(rs, 4);
      rs += __shfl_xor(rs, 8);
      l_r[r] += rs;
    }

    // ---- P -> per-wave LDS (swizzled), re-fragment as PV A-operand
#pragma unroll
    for (int r = 0; r < 4; ++r) {
      const int pr = r4 + r;
      const int sw = (pr & 7) << 4;
#pragma unroll
      for (int j = 0; j < 4; ++j)
        *reinterpret_cast<bf16*>(pw + pr * 128 + ((j * 32 + 2 * l15) ^ sw)) = (bf16)sf[j][r];
    }

    // ---- O += P V
#pragma unroll
    for (int kk = 0; kk < 2; ++kk) {
      bf16x8 vb[4];
#pragma unroll
      for (int j = 0; j < 4; ++j) {
        const int vr = j * 16 + l15;
        vb[j] = *reinterpret_cast<const bf16x8*>(
            Vc + vr * 128 + ((kk * 64 + 16 * lg) ^ ((vr & 7) << 4)));
      }
      const bf16x8 pa = *reinterpret_cast<const bf16x8*>(
          pw + l15 * 128 + ((kk * 64 + 16 * lg) ^ ((l15 & 7) << 4)));
      __builtin_amdgcn_s_setprio(1);
#pragma unroll
      for (int j = 0; j < 4; ++j)
        o[j] = __builtin_amdgcn_mfma_f32_16x16x32_bf16(pa, vb[j], o[j], 0, 0, 0);
      __builtin_amdgcn_s_setprio(0);
    }
    // no trailing barrier: 3-buffer rotation makes next STAGE safe
  }

  // ---- normalize + write [b][s][h*64+d]
  const int b = bh >> 4, h = bh & 15;
#pragma unroll
  for (int r = 0; r < 4; ++r) {
    const float inv = 1.0f / l_r[r];
    const int srow = q0 + wid * 16 + r4 + r;
    bf16* obase = O + ((size_t)(b * S_LEN + srow)) * DM + h * DK;
#pragma unroll
    for (int j = 0; j < 4; ++j) obase[j * 16 + l15] = (bf16)(o[j][r] * inv);
  }
}

// ---------------------------------------------------------------- out proj
__global__ __launch_bounds__(256) void gemm_out(
    const bf16* __restrict__ A, const bf16* __restrict__ W,
    const float* __restrict__ bias, float* __restrict__ C) {
  __shared__ char smem[65536];
  const int m0 = blockIdx.y * 128, n0 = blockIdx.x * 128;
  const int tid = threadIdx.x, lane = tid & 63, wid = tid >> 6;
  const int wr = (wid >> 1) * 64, wc = (wid & 1) * 64;
  const int scb = 16 * ((lane & 7) ^ (lane >> 3));
  const int lr8 = lane >> 3;
  f32x4 acc[4][4] = {};

  auto STAGE = [&](int bi, int k0) {
#pragma unroll
    for (int c = 0; c < 4; ++c) {
      const int chunk = wid * 4 + c;
      const int row = chunk * 8 + lr8;
      gld16((const char*)A + ((size_t)(m0 + row) * DM + k0) * 2 + scb,
            smem + bi * 32768 + chunk * 1024);
      gld16((const char*)W + ((size_t)(n0 + row) * DM + k0) * 2 + scb,
            smem + bi * 32768 + 16384 + chunk * 1024);
    }
  };

  STAGE(0, 0);
  asm volatile("s_waitcnt vmcnt(0)" ::: "memory");
  __builtin_amdgcn_s_barrier();

  const int NK = DM / 64;
  for (int it = 0; it < NK; ++it) {
    if (it + 1 < NK) STAGE((it + 1) & 1, (it + 1) * 64);
    const char* As = smem + (it & 1) * 32768;
    const char* Bs = As + 16384;
#pragma unroll
    for (int kk = 0; kk < 2; ++kk) {
      bf16x8 af[4], bfr[4];
#pragma unroll
      for (int i = 0; i < 4; ++i) {
        const int ar = wr + i * 16 + (lane & 15);
        af[i] = *reinterpret_cast<const bf16x8*>(
            As + ar * 128 + ((kk * 64 + 16 * (lane >> 4)) ^ ((ar & 7) << 4)));
        const int br = wc + i * 16 + (lane & 15);
        bfr[i] = *reinterpret_cast<const bf16x8*>(
            Bs + br * 128 + ((kk * 64 + 16 * (lane >> 4)) ^ ((br & 7) << 4)));
      }
      __builtin_amdgcn_s_setprio(1);
#pragma unroll
      for (int i = 0; i < 4; ++i)
#pragma unroll
        for (int j = 0; j < 4; ++j)
          acc[i][j] = __builtin_amdgcn_mfma_f32_16x16x32_bf16(af[i], bfr[j], acc[i][j], 0, 0, 0);
      __builtin_amdgcn_s_setprio(0);
    }
    asm volatile("s_waitcnt vmcnt(0)" ::: "memory");
    __builtin_amdgcn_s_barrier();
  }

  const int r4 = (lane >> 4) * 4;
#pragma unroll
  for (int i = 0; i < 4; ++i) {
    const int mrow = m0 + wr + i * 16 + r4;
#pragma unroll
    for (int j = 0; j < 4; ++j) {
      const int n = n0 + wc + j * 16 + (lane & 15);
      const float bs = bias[n];
#pragma unroll
      for (int r = 0; r < 4; ++r) C[(size_t)(mrow + r) * DM + n] = acc[i][j][r] + bs;
    }
  }
}

// ---------------------------------------------------------------- launcher
extern "C" void kernel_launch(void* const* d_in, const int* in_sizes, int n_in,
                              void* d_out, int out_size, void* d_ws, size_t ws_size,
                              hipStream_t stream) {
  const float* x = (const float*)d_in[0];
  const float* Wq = (const float*)d_in[2];
  const float* bq = (const float*)d_in[3];
  const float* Wk = (const float*)d_in[4];
  const float* bk = (const float*)d_in[5];
  const float* Wv = (const float*)d_in[6];
  const float* bv = (const float*)d_in[7];
  const float* Wo = (const float*)d_in[8];
  const float* bo = (const float*)d_in[9];

  char* ws = (char*)d_ws;  // needs 48 MB
  bf16* xb  = (bf16*)(ws);
  bf16* wqb = (bf16*)(ws + (8u << 20));
  bf16* wkb = (bf16*)(ws + (10u << 20));
  bf16* wvb = (bf16*)(ws + (12u << 20));
  bf16* wob = (bf16*)(ws + (14u << 20));
  bf16* Qw  = (bf16*)(ws + (16u << 20));
  bf16* Kw  = (bf16*)(ws + (24u << 20));
  bf16* Vtw = (bf16*)(ws + (32u << 20));
  bf16* AO  = (bf16*)(ws + (40u << 20));

  cvt_all<<<8192, 256, 0, stream>>>(x, Wq, Wk, Wv, Wo, xb, wqb, wkb, wvb, wob);

  gemm_qkv<<<dim3(DM / 128, MTOK / 128, 3), 256, 0, stream>>>(
      xb, wqb, wkb, wvb, bq, bk, bv, Qw, Kw, Vtw);
  attn_fwd<<<dim3((S_LEN / 128) * 32), 512, 0, stream>>>(Qw, Kw, Vtw, AO);
  gemm_out<<<dim3(DM / 128, MTOK / 128), 256, 0, stream>>>(AO, wob, bo, (float*)d_out);
}

// Round 8
// 118.615 us; speedup vs baseline: 1.7440x; 1.1524x over previous
//
#include <hip/hip_runtime.h>
#include <hip/hip_bf16.h>

typedef __bf16 bf16;
typedef bf16 bf16x8 __attribute__((ext_vector_type(8)));
typedef bf16 bf16x4 __attribute__((ext_vector_type(4)));
typedef float f32x4 __attribute__((ext_vector_type(4)));
typedef float f32x16 __attribute__((ext_vector_type(16)));
typedef unsigned int u32;
typedef u32 u32x4 __attribute__((ext_vector_type(4)));

#define S_LEN 2048
#define DM 1024
#define NH 16
#define DK 64
#define MTOK 4096  // B*S

// async global->LDS, 16B per lane; LDS dest is wave-uniform base + lane*16
__device__ __forceinline__ void gld16(const void* g, void* l) {
  __builtin_amdgcn_global_load_lds(
      (const __attribute__((address_space(1))) u32*)g,
      (__attribute__((address_space(3))) u32*)l, 16, 0, 0);
}

// pack two f32 -> u32 of two bf16 (compiler emits cvt_pk)
__device__ __forceinline__ u32 pkbf(float lo, float hi) {
  union { bf16 h[2]; u32 u; } c;
  c.h[0] = (bf16)lo; c.h[1] = (bf16)hi;
  return c.u;
}
// v_permlane32_swap_b32 a, b:  a_hi <-> b_lo  (a keeps its low half, b keeps
// its high half) — 2x2 block transpose of [[a_lo,a_hi],[b_lo,b_hi]].
__device__ __forceinline__ void plswap(u32& a, u32& b) {
  asm volatile("v_permlane32_swap_b32 %0, %1" : "+v"(a), "+v"(b));
}

// ---------------------------------------------------------------- convert
__global__ __launch_bounds__(256) void cvt_all(
    const float* __restrict__ x, const float* __restrict__ wq, const float* __restrict__ wk,
    const float* __restrict__ wv, const float* __restrict__ wo,
    bf16* __restrict__ xb, bf16* __restrict__ wqb, bf16* __restrict__ wkb,
    bf16* __restrict__ wvb, bf16* __restrict__ wob) {
  const int i = blockIdx.x * blockDim.x + threadIdx.x;
  const int NX = (MTOK * DM) / 4;
  const int NW = (DM * DM) / 4;
  const float* src;
  bf16* dst;
  int off;
  if (i < NX) {
    src = x; dst = xb; off = i;
  } else {
    const int j = i - NX;
    const int w = j >> 18;
    off = j & (NW - 1);
    src = (w == 0) ? wq : (w == 1) ? wk : (w == 2) ? wv : wo;
    dst = (w == 0) ? wqb : (w == 1) ? wkb : (w == 2) ? wvb : wob;
  }
  f32x4 v = reinterpret_cast<const f32x4*>(src)[off];
  bf16x4 o;
  o[0] = (bf16)v[0]; o[1] = (bf16)v[1]; o[2] = (bf16)v[2]; o[3] = (bf16)v[3];
  reinterpret_cast<bf16x4*>(dst)[off] = o;
}

// ---------------------------------------------------------------- QKV GEMM
__global__ __launch_bounds__(256) void gemm_qkv(
    const bf16* __restrict__ A,
    const bf16* __restrict__ Wq, const bf16* __restrict__ Wk, const bf16* __restrict__ Wv,
    const float* __restrict__ Bq, const float* __restrict__ Bk, const float* __restrict__ Bv,
    bf16* __restrict__ Qo, bf16* __restrict__ Ko, bf16* __restrict__ Vt) {
  __shared__ char smem[65536];
  const int z = blockIdx.z;
  const bf16* W = (z == 0) ? Wq : (z == 1) ? Wk : Wv;
  const float* bias = (z == 0) ? Bq : (z == 1) ? Bk : Bv;
  const int m0 = blockIdx.y * 128;
  const int n0 = blockIdx.x * 128;
  const int tid = threadIdx.x;
  const int lane = tid & 63;
  const int wid = tid >> 6;
  const int wr = (wid >> 1) * 64, wc = (wid & 1) * 64;
  const int scb = 16 * ((lane & 7) ^ (lane >> 3));
  const int lr8 = lane >> 3;

  f32x4 acc[4][4] = {};

  auto STAGE = [&](int bi, int k0) {
#pragma unroll
    for (int c = 0; c < 4; ++c) {
      const int chunk = wid * 4 + c;
      const int row = chunk * 8 + lr8;
      gld16((const char*)A + ((size_t)(m0 + row) * DM + k0) * 2 + scb,
            smem + bi * 32768 + chunk * 1024);
      gld16((const char*)W + ((size_t)(n0 + row) * DM + k0) * 2 + scb,
            smem + bi * 32768 + 16384 + chunk * 1024);
    }
  };

  STAGE(0, 0);
  asm volatile("s_waitcnt vmcnt(0)" ::: "memory");
  __builtin_amdgcn_s_barrier();

  const int NK = DM / 64;  // 16
  for (int it = 0; it < NK; ++it) {
    if (it + 1 < NK) STAGE((it + 1) & 1, (it + 1) * 64);
    const char* As = smem + (it & 1) * 32768;
    const char* Bs = As + 16384;
#pragma unroll
    for (int kk = 0; kk < 2; ++kk) {
      bf16x8 af[4], bfr[4];
#pragma unroll
      for (int i = 0; i < 4; ++i) {
        const int ar = wr + i * 16 + (lane & 15);
        af[i] = *reinterpret_cast<const bf16x8*>(
            As + ar * 128 + ((kk * 64 + 16 * (lane >> 4)) ^ ((ar & 7) << 4)));
        const int br = wc + i * 16 + (lane & 15);
        bfr[i] = *reinterpret_cast<const bf16x8*>(
            Bs + br * 128 + ((kk * 64 + 16 * (lane >> 4)) ^ ((br & 7) << 4)));
      }
      __builtin_amdgcn_s_setprio(1);
#pragma unroll
      for (int i = 0; i < 4; ++i)
#pragma unroll
        for (int j = 0; j < 4; ++j)
          acc[i][j] = __builtin_amdgcn_mfma_f32_16x16x32_bf16(af[i], bfr[j], acc[i][j], 0, 0, 0);
      __builtin_amdgcn_s_setprio(0);
    }
    asm volatile("s_waitcnt vmcnt(0)" ::: "memory");
    __builtin_amdgcn_s_barrier();
  }

  // Q pre-scale: 1/sqrt(dk) * log2(e)  (attn softmax runs in exp2 domain)
  const float QSC = 0.125f * 1.44269504089f;
  const int bIdx = m0 >> 11;
  const int r4 = (lane >> 4) * 4;
#pragma unroll
  for (int i = 0; i < 4; ++i) {
    const int mrow = m0 + wr + i * 16 + r4;
    const int srow = mrow & (S_LEN - 1);
#pragma unroll
    for (int j = 0; j < 4; ++j) {
      const int n = n0 + wc + j * 16 + (lane & 15);
      const int h = n >> 6, d = n & 63;
      const int bh = bIdx * NH + h;
      const float bs = bias[n];
      if (z == 0) {
#pragma unroll
        for (int r = 0; r < 4; ++r)
          Qo[((size_t)bh * S_LEN + srow + r) * DK + d] = (bf16)((acc[i][j][r] + bs) * QSC);
      } else if (z == 1) {
#pragma unroll
        for (int r = 0; r < 4; ++r)
          Ko[((size_t)bh * S_LEN + srow + r) * DK + d] = (bf16)(acc[i][j][r] + bs);
      } else {
        bf16x4 pk;
#pragma unroll
        for (int r = 0; r < 4; ++r) pk[r] = (bf16)(acc[i][j][r] + bs);
        *reinterpret_cast<bf16x4*>(&Vt[((size_t)bh * DK + d) * S_LEN + srow]) = pk;
      }
    }
  }
}

// ---------------------------------------------------------------- attention
// 32x32 swapped-operand structure: 4 waves x 32 q-rows (QBLK=128), KVBLK=64,
// 3-buffer/1-barrier, counted vmcnt(4). Softmax fully in-register:
// S^T = mfma32(K,Q) puts one query per lane (col=lane&31); P->PV B-operand via
// cvt_pk + permlane32_swap; O^T = mfma32(V^T,P^T) keeps everything lane-local.
__global__ __launch_bounds__(256) void attn_fwd(
    const bf16* __restrict__ Q, const bf16* __restrict__ K,
    const bf16* __restrict__ Vt, bf16* __restrict__ O) {
  __shared__ char smem[49152];  // buf i<3: K at i*16384 (8KB), V at +8192 (8KB)

  const int bid = blockIdx.x;
  const int qt = 15 - (bid >> 5);  // heavy q-tiles first
  const int bh = bid & 31;
  const int tid = threadIdx.x, lane = tid & 63, wid = tid >> 6;
  const int q0 = qt * 128;
  const int scb = 16 * ((lane & 7) ^ (lane >> 3));
  const int l31 = lane & 31;
  const int hi = lane >> 5;
  const int qrow = q0 + wid * 32 + l31;
  const int swz = (l31 & 7) << 4;

  // Q fragments: B-operand of mfma32 (col=q, k = 16*ks + 8*hi + j)
  const bf16* qb = Q + ((size_t)bh * S_LEN + qrow) * DK;
  bf16x8 qf[4];
#pragma unroll
  for (int ks = 0; ks < 4; ++ks)
    qf[ks] = *reinterpret_cast<const bf16x8*>(qb + ks * 16 + 8 * hi);

  f32x16 o0 = {}, o1 = {};  // O^T: row d = (r&3)+8*(r>>2)+4*hi (+32*dt), col q = l31
  float m_r = -3.0e38f, l_r = 0.f;

  const int nt = 2 * (qt + 1);

  auto STAGE = [&](int bi, int t) {
    const int kv0 = t * 64;
#pragma unroll
    for (int c = 0; c < 2; ++c) {
      const int chunk = wid * 2 + c;  // 8 chunks x 1KB each for K and V
      const int row = chunk * 8 + (lane >> 3);
      gld16((const char*)K + ((size_t)(bh * S_LEN + kv0 + row)) * 128 + scb,
            smem + bi * 16384 + chunk * 1024);
      gld16((const char*)Vt + ((size_t)(bh * DK + row)) * (S_LEN * 2) + (size_t)kv0 * 2 + scb,
            smem + bi * 16384 + 8192 + chunk * 1024);
    }
  };

  STAGE(0, 0);

  for (int t = 0; t < nt; ++t) {
    const int kv0 = t * 64;
    if (t + 1 < nt) {
      STAGE((t + 1) % 3, t + 1);
      asm volatile("s_waitcnt vmcnt(4)" ::: "memory");
    } else {
      asm volatile("s_waitcnt vmcnt(0)" ::: "memory");
    }
    __builtin_amdgcn_s_barrier();
    asm volatile("" ::: "memory");
    const char* Kc = smem + (t % 3) * 16384;
    const char* Vc = Kc + 8192;

    // ---- S^T = K Q^T : per lane one query (l31), keys crow(r,hi)+32*kt
    f32x16 s0 = {}, s1 = {};
#pragma unroll
    for (int kt = 0; kt < 2; ++kt) {
      bf16x8 ka[4];
#pragma unroll
      for (int ks = 0; ks < 4; ++ks)
        ka[ks] = *reinterpret_cast<const bf16x8*>(
            Kc + (kt * 32 + l31) * 128 + ((ks * 32 + 16 * hi) ^ swz));
      f32x16& sd = kt ? s1 : s0;
      __builtin_amdgcn_s_setprio(1);
#pragma unroll
      for (int ks = 0; ks < 4; ++ks)
        sd = __builtin_amdgcn_mfma_f32_32x32x16_bf16(ka[ks], qf[ks], sd, 0, 0, 0);
      __builtin_amdgcn_s_setprio(0);
    }

    if (t >= nt - 2) {  // diagonal tiles: causal mask
#pragma unroll
      for (int r = 0; r < 16; ++r) {
        const int key0 = kv0 + (r & 3) + 8 * (r >> 2) + 4 * hi;
        if (key0 > qrow) s0[r] = -1.0e9f;
        if (key0 + 32 > qrow) s1[r] = -1.0e9f;
      }
    }

    // ---- in-register softmax (exp2 domain, defer-max THR=8, wave-uniform)
    float mx = s0[0];
#pragma unroll
    for (int r = 1; r < 16; ++r) mx = fmaxf(mx, s0[r]);
#pragma unroll
    for (int r = 0; r < 16; ++r) mx = fmaxf(mx, s1[r]);
    mx = fmaxf(mx, __shfl_xor(mx, 32));
    if (!__all(mx <= m_r + 8.f)) {
      const float nm = fmaxf(m_r, mx);
      const float sc = exp2f(m_r - nm);
      l_r *= sc;
      o0 *= sc;
      o1 *= sc;
      m_r = nm;
    }
    float rs = 0.f;
#pragma unroll
    for (int r = 0; r < 16; ++r) { s0[r] = exp2f(s0[r] - m_r); rs += s0[r]; }
#pragma unroll
    for (int r = 0; r < 16; ++r) { s1[r] = exp2f(s1[r] - m_r); rs += s1[r]; }
    rs += __shfl_xor(rs, 32);
    l_r += rs;

    // ---- pack P^T B-operand fragments: pb[ks] elem j <-> key 16*ks+8*hi+j
    // plswap(a,b): a_hi <-> b_lo.  plswap(cA,cC) => cA=[own k0,k1 | partner k8,k9-slot],
    // cC=[partner k4,k5-slot | own k12,k13-slot] -- exact (hi,j)->key map.
    bf16x8 pb[4];
#pragma unroll
    for (int kt = 0; kt < 2; ++kt) {
      const f32x16& p = kt ? s1 : s0;
#pragma unroll
      for (int s2 = 0; s2 < 2; ++s2) {
        u32 cA = pkbf(p[8 * s2 + 0], p[8 * s2 + 1]);
        u32 cB = pkbf(p[8 * s2 + 2], p[8 * s2 + 3]);
        u32 cC = pkbf(p[8 * s2 + 4], p[8 * s2 + 5]);
        u32 cD = pkbf(p[8 * s2 + 6], p[8 * s2 + 7]);
        plswap(cA, cC);
        plswap(cB, cD);
        u32x4 w;
        w[0] = cA; w[1] = cB; w[2] = cC; w[3] = cD;
        pb[kt * 2 + s2] = __builtin_bit_cast(bf16x8, w);
      }
    }

    // ---- O^T += V^T P^T  (A row = d, from Vs[d][kv]; B col = q)
#pragma unroll
    for (int dt = 0; dt < 2; ++dt) {
      bf16x8 va[4];
#pragma unroll
      for (int ks = 0; ks < 4; ++ks)
        va[ks] = *reinterpret_cast<const bf16x8*>(
            Vc + (dt * 32 + l31) * 128 + ((ks * 32 + 16 * hi) ^ swz));
      f32x16& od = dt ? o1 : o0;
      __builtin_amdgcn_s_setprio(1);
#pragma unroll
      for (int ks = 0; ks < 4; ++ks)
        od = __builtin_amdgcn_mfma_f32_32x32x16_bf16(va[ks], pb[ks], od, 0, 0, 0);
      __builtin_amdgcn_s_setprio(0);
    }
    // no trailing barrier: 3-buffer rotation makes next STAGE safe
  }

  // ---- normalize (lane-local!) + write [b][s][h*64+d]
  const int b = bh >> 4, h = bh & 15;
  const float inv = 1.0f / l_r;
  bf16* obase = O + ((size_t)(b * S_LEN + qrow)) * DM + h * DK;
#pragma unroll
  for (int dt = 0; dt < 2; ++dt) {
    const f32x16& od = dt ? o1 : o0;
#pragma unroll
    for (int g = 0; g < 4; ++g) {
      bf16x4 pk4;
#pragma unroll
      for (int m = 0; m < 4; ++m) pk4[m] = (bf16)(od[4 * g + m] * inv);
      *reinterpret_cast<bf16x4*>(obase + dt * 32 + 8 * g + 4 * hi) = pk4;
    }
  }
}

// ---------------------------------------------------------------- out proj
__global__ __launch_bounds__(256) void gemm_out(
    const bf16* __restrict__ A, const bf16* __restrict__ W,
    const float* __restrict__ bias, float* __restrict__ C) {
  __shared__ char smem[65536];
  const int m0 = blockIdx.y * 128, n0 = blockIdx.x * 128;
  const int tid = threadIdx.x, lane = tid & 63, wid = tid >> 6;
  const int wr = (wid >> 1) * 64, wc = (wid & 1) * 64;
  const int scb = 16 * ((lane & 7) ^ (lane >> 3));
  const int lr8 = lane >> 3;
  f32x4 acc[4][4] = {};

  auto STAGE = [&](int bi, int k0) {
#pragma unroll
    for (int c = 0; c < 4; ++c) {
      const int chunk = wid * 4 + c;
      const int row = chunk * 8 + lr8;
      gld16((const char*)A + ((size_t)(m0 + row) * DM + k0) * 2 + scb,
            smem + bi * 32768 + chunk * 1024);
      gld16((const char*)W + ((size_t)(n0 + row) * DM + k0) * 2 + scb,
            smem + bi * 32768 + 16384 + chunk * 1024);
    }
  };

  STAGE(0, 0);
  asm volatile("s_waitcnt vmcnt(0)" ::: "memory");
  __builtin_amdgcn_s_barrier();

  const int NK = DM / 64;
  for (int it = 0; it < NK; ++it) {
    if (it + 1 < NK) STAGE((it + 1) & 1, (it + 1) * 64);
    const char* As = smem + (it & 1) * 32768;
    const char* Bs = As + 16384;
#pragma unroll
    for (int kk = 0; kk < 2; ++kk) {
      bf16x8 af[4], bfr[4];
#pragma unroll
      for (int i = 0; i < 4; ++i) {
        const int ar = wr + i * 16 + (lane & 15);
        af[i] = *reinterpret_cast<const bf16x8*>(
            As + ar * 128 + ((kk * 64 + 16 * (lane >> 4)) ^ ((ar & 7) << 4)));
        const int br = wc + i * 16 + (lane & 15);
        bfr[i] = *reinterpret_cast<const bf16x8*>(
            Bs + br * 128 + ((kk * 64 + 16 * (lane >> 4)) ^ ((br & 7) << 4)));
      }
      __builtin_amdgcn_s_setprio(1);
#pragma unroll
      for (int i = 0; i < 4; ++i)
#pragma unroll
        for (int j = 0; j < 4; ++j)
          acc[i][j] = __builtin_amdgcn_mfma_f32_16x16x32_bf16(af[i], bfr[j], acc[i][j], 0, 0, 0);
      __builtin_amdgcn_s_setprio(0);
    }
    asm volatile("s_waitcnt vmcnt(0)" ::: "memory");
    __builtin_amdgcn_s_barrier();
  }

  const int r4 = (lane >> 4) * 4;
#pragma unroll
  for (int i = 0; i < 4; ++i) {
    const int mrow = m0 + wr + i * 16 + r4;
#pragma unroll
    for (int j = 0; j < 4; ++j) {
      const int n = n0 + wc + j * 16 + (lane & 15);
      const float bs = bias[n];
#pragma unroll
      for (int r = 0; r < 4; ++r) C[(size_t)(mrow + r) * DM + n] = acc[i][j][r] + bs;
    }
  }
}

// ---------------------------------------------------------------- launcher
extern "C" void kernel_launch(void* const* d_in, const int* in_sizes, int n_in,
                              void* d_out, int out_size, void* d_ws, size_t ws_size,
                              hipStream_t stream) {
  const float* x = (const float*)d_in[0];
  const float* Wq = (const float*)d_in[2];
  const float* bq = (const float*)d_in[3];
  const float* Wk = (const float*)d_in[4];
  const float* bk = (const float*)d_in[5];
  const float* Wv = (const float*)d_in[6];
  const float* bv = (const float*)d_in[7];
  const float* Wo = (const float*)d_in[8];
  const float* bo = (const float*)d_in[9];

  char* ws = (char*)d_ws;  // needs 48 MB
  bf16* xb  = (bf16*)(ws);
  bf16* wqb = (bf16*)(ws + (8u << 20));
  bf16* wkb = (bf16*)(ws + (10u << 20));
  bf16* wvb = (bf16*)(ws + (12u << 20));
  bf16* wob = (bf16*)(ws + (14u << 20));
  bf16* Qw  = (bf16*)(ws + (16u << 20));
  bf16* Kw  = (bf16*)(ws + (24u << 20));
  bf16* Vtw = (bf16*)(ws + (32u << 20));
  bf16* AO  = (bf16*)(ws + (40u << 20));

  cvt_all<<<8192, 256, 0, stream>>>(x, Wq, Wk, Wv, Wo, xb, wqb, wkb, wvb, wob);

  gemm_qkv<<<dim3(DM / 128, MTOK / 128, 3), 256, 0, stream>>>(
      xb, wqb, wkb, wvb, bq, bk, bv, Qw, Kw, Vtw);
  attn_fwd<<<dim3(512), 256, 0, stream>>>(Qw, Kw, Vtw, AO);
  gemm_out<<<dim3(DM / 128, MTOK / 128), 256, 0, stream>>>(AO, wob, bo, (float*)d_out);
}